// Round 1
// baseline (253.358 us; speedup 1.0000x reference)
//
#include <hip/hip_runtime.h>
#include <math.h>

#define O_ 3
#define P_ 128
#define G_ 64
#define N_ 20000
#define H_ 512
#define D_ 128
#define M_ (O_*P_)          // 384 anchors
#define R_ 4                // rows per block in fused gather+GEMM1

static constexpr float TEMP_INV = 10.0f;   // 1/0.1
static constexpr float EPS_ = 1e-12f;

// ---------------------------------------------------------------------------
// KA: fused gather+mean (protos) + GEMM1 + ReLU.
// 96 blocks = 3 omics x 32 row-groups of R_=4 rows; 512 threads.
// Phase 1: thread t owns (row r = t>>7, float4 col c4 = t&127); gathers 64
//   emb rows with unroll 16 (16 outstanding 16B loads/lane), mean into LDS.
// Phase 2: thread t = output k; protos read from LDS (broadcast, no conflict),
//   W1 reads coalesced across k. Eliminates protos global round-trip + launch.
// ---------------------------------------------------------------------------
__global__ __launch_bounds__(512) void k_proto_gemm1(const float* __restrict__ emb,
                                                     const int* __restrict__ idx,
                                                     const float* __restrict__ W1,
                                                     const float* __restrict__ b1,
                                                     float* __restrict__ hbuf) {
    const int blk = blockIdx.x;               // o*32 + pg
    const int o = blk >> 5, pg = blk & 31;
    const int p0 = pg * R_;
    const int t = threadIdx.x;                // 0..511

    __shared__ int   sIdx[R_][G_];            // 1 KB
    __shared__ float sPr[R_][H_];             // 8 KB

    if (t < R_ * G_)
        sIdx[t >> 6][t & 63] = idx[(o * P_ + p0 + (t >> 6)) * G_ + (t & 63)];
    __syncthreads();

    // ---- phase 1: gather + mean ----
    {
        const int r = t >> 7, c4 = t & 127;
        const float* base = emb + (size_t)o * N_ * H_ + (size_t)c4 * 4;
        float4 acc = make_float4(0.f, 0.f, 0.f, 0.f);
        #pragma unroll 16
        for (int g = 0; g < G_; ++g) {
            const float4 v = *(const float4*)(base + (size_t)((unsigned)sIdx[r][g]) * H_);
            acc.x += v.x; acc.y += v.y; acc.z += v.z; acc.w += v.w;
        }
        const float s = 1.0f / (float)G_;
        ((float4*)sPr[r])[c4] = make_float4(acc.x * s, acc.y * s, acc.z * s, acc.w * s);
    }
    __syncthreads();

    // ---- phase 2: GEMM1 (4 rows) + ReLU ----
    const int k = t;
    const float bias = b1[o * H_ + k];
    float acc0 = bias, acc1 = bias, acc2 = bias, acc3 = bias;
    const float* w1 = W1 + (size_t)o * H_ * H_ + k;
    const float4* p0v = (const float4*)sPr[0];
    const float4* p1v = (const float4*)sPr[1];
    const float4* p2v = (const float4*)sPr[2];
    const float4* p3v = (const float4*)sPr[3];

    #pragma unroll 2
    for (int h4 = 0; h4 < H_ / 4; ++h4) {
        const float4 a0 = p0v[h4];
        const float4 a1 = p1v[h4];
        const float4 a2 = p2v[h4];
        const float4 a3 = p3v[h4];
        const float w_0 = w1[(size_t)(h4 * 4 + 0) * H_];
        const float w_1 = w1[(size_t)(h4 * 4 + 1) * H_];
        const float w_2 = w1[(size_t)(h4 * 4 + 2) * H_];
        const float w_3 = w1[(size_t)(h4 * 4 + 3) * H_];
        acc0 = fmaf(a0.x, w_0, fmaf(a0.y, w_1, fmaf(a0.z, w_2, fmaf(a0.w, w_3, acc0))));
        acc1 = fmaf(a1.x, w_0, fmaf(a1.y, w_1, fmaf(a1.z, w_2, fmaf(a1.w, w_3, acc1))));
        acc2 = fmaf(a2.x, w_0, fmaf(a2.y, w_1, fmaf(a2.z, w_2, fmaf(a2.w, w_3, acc2))));
        acc3 = fmaf(a3.x, w_0, fmaf(a3.y, w_1, fmaf(a3.z, w_2, fmaf(a3.w, w_3, acc3))));
    }
    float* hb = hbuf + (size_t)(o * P_ + p0) * H_ + k;
    hb[0 * H_] = fmaxf(acc0, 0.f);
    hb[1 * H_] = fmaxf(acc1, 0.f);
    hb[2 * H_] = fmaxf(acc2, 0.f);
    hb[3 * H_] = fmaxf(acc3, 0.f);
}

// ---------------------------------------------------------------------------
// KB: z = (hbuf @ W2 + b2), then l2-normalize each row; store in anchor order
// m = p*3 + o. 384 blocks (one per (o,p)), 128 threads, thread = output d.
// h-row staged in LDS (coalesced float4) instead of per-thread broadcast loads.
// ---------------------------------------------------------------------------
__global__ __launch_bounds__(128) void k_gemm2_norm(const float* __restrict__ hbuf,
                                                    const float* __restrict__ W2,
                                                    const float* __restrict__ b2,
                                                    float* __restrict__ z) {
    const int b = blockIdx.x;            // o*128 + p
    const int o = b >> 7, p = b & 127;
    const int d = threadIdx.x;

    __shared__ float sh[H_];
    ((float4*)sh)[d] = ((const float4*)(hbuf + (size_t)b * H_))[d];
    __syncthreads();

    const float* w2 = W2 + (size_t)o * H_ * D_ + d;
    float acc = b2[o * D_ + d];
    #pragma unroll 8
    for (int kk = 0; kk < H_; ++kk)
        acc = fmaf(sh[kk], w2[(size_t)kk * D_], acc);

    // row norm across the 128 threads (2 waves)
    float s = acc * acc;
    #pragma unroll
    for (int off = 32; off > 0; off >>= 1) s += __shfl_down(s, off, 64);
    __shared__ float red[2];
    const int lane = d & 63, wid = d >> 6;
    if (lane == 0) red[wid] = s;
    __syncthreads();
    const float nrm = sqrtf(red[0] + red[1]);
    const float inv = 1.0f / (nrm + EPS_);
    z[(size_t)(p * O_ + o) * D_ + d] = acc * inv;
}

// ---------------------------------------------------------------------------
// KC: supervised-contrastive loss. One block per anchor i (384 blocks, 128 thr).
// Thread t handles j in {t, t+128, t+256}: dot(z_i, z_j), exp(dot*10),
// accumulate denom and positive sums; block-reduce; atomicAdd(loss/384).
// ---------------------------------------------------------------------------
__global__ __launch_bounds__(128) void k_loss(const float* __restrict__ z,
                                              float* __restrict__ out) {
    const int i = blockIdx.x;            // 0..383
    const int t = threadIdx.x;
    __shared__ float zi[D_];
    zi[t] = z[(size_t)i * D_ + t];
    __syncthreads();
    const int pi = i / 3;                // pathway label of anchor
    float denom = 0.f, pos = 0.f;
    const float4* zi4 = (const float4*)zi;
    #pragma unroll
    for (int jj = 0; jj < 3; ++jj) {
        const int j = t + jj * 128;
        const float4* zj = (const float4*)(z + (size_t)j * D_);
        float dot = 0.f;
        #pragma unroll 8
        for (int q = 0; q < D_ / 4; ++q) {
            const float4 a = zi4[q];
            const float4 bb = zj[q];
            dot = fmaf(a.x, bb.x, fmaf(a.y, bb.y, fmaf(a.z, bb.z, fmaf(a.w, bb.w, dot))));
        }
        if (j != i) {
            const float e = __expf(dot * TEMP_INV);
            denom += e;
            if (j / 3 == pi) pos += e;
        }
    }
    #pragma unroll
    for (int off = 32; off > 0; off >>= 1) {
        denom += __shfl_down(denom, off, 64);
        pos   += __shfl_down(pos,   off, 64);
    }
    __shared__ float rd[2], rp[2];
    const int lane = t & 63, wid = t >> 6;
    if (lane == 0) { rd[wid] = denom; rp[wid] = pos; }
    __syncthreads();
    if (t == 0) {
        const float dn = rd[0] + rd[1] + EPS_;
        const float ps = rp[0] + rp[1] + EPS_;
        const float loss_i = logf(dn) - logf(ps);   // = -log(pos/denom)
        atomicAdd(out, loss_i * (1.0f / (float)M_));
    }
}

// ---------------------------------------------------------------------------
extern "C" void kernel_launch(void* const* d_in, const int* in_sizes, int n_in,
                              void* d_out, int out_size, void* d_ws, size_t ws_size,
                              hipStream_t stream) {
    const float* emb = (const float*)d_in[0];   // [3,20000,512]
    const float* W1  = (const float*)d_in[1];   // [3,512,512]
    const float* b1  = (const float*)d_in[2];   // [3,512]
    const float* W2  = (const float*)d_in[3];   // [3,512,128]
    const float* b2  = (const float*)d_in[4];   // [3,128]
    const int*   idx = (const int*)d_in[5];     // [3,128,64]

    float* ws   = (float*)d_ws;
    float* hbuf = ws;                           // 384*512 = 196608 floats
    float* zbuf = ws + 196608;                  // 384*128 =  49152 floats

    // d_out is re-poisoned to 0xAA before every replay: zero it in-graph.
    hipMemsetAsync(d_out, 0, sizeof(float), stream);

    k_proto_gemm1<<<dim3(96),  dim3(512), 0, stream>>>(emb, idx, W1, b1, hbuf);
    k_gemm2_norm <<<dim3(M_),  dim3(128), 0, stream>>>(hbuf, W2, b2, zbuf);
    k_loss       <<<dim3(M_),  dim3(128), 0, stream>>>(zbuf, (float*)d_out);
}